// Round 6
// baseline (267.749 us; speedup 1.0000x reference)
//
#include <hip/hip_runtime.h>

// Problem constants (match reference)
#define B 32
#define S 32
#define N 128
#define U 64
#define E 2
#define NCLS 5
#define NBLK 4   // blocks per batch (4-way flag barrier)
#define RPW 4    // rows per wave (8 waves x 4 rows = 32 rows per block)

// R13: ONE kernel, per-batch 4-block flag barriers. Evidence: R8/R9/R12 inner
// restructures all neutral (210-225us); R11 gave the only hard number:
// VALU ~3.7us/step, and (414 - 6x~55us grid.sync)/6 => in-kernel step ~14us
// -> the 7-dispatch path carries ~17us/boundary of launch dead time (~120us).
// Fix: remove dispatch boundaries. Only cross-block dep is within a batch
// (aggregate reads all rows of h[b]), so 32 independent 4-block groups sync
// via private device-scope monotonic flags (release fence + atomicAdd +
// acquire spin), never a full grid.sync. 128 blocks x 512 thr co-resident by
// construction; bounded spin turns protocol bugs into wrong answers, not
// hangs. Per-row FMA order identical to R9 -> bit-identical h.

__device__ __forceinline__ float sigmoid_f(float x) {
    return __fdividef(1.f, 1.f + __expf(-x));
}
__device__ __forceinline__ float tanh_f(float x) {
    float t = __expf(-2.f * fabsf(x));
    float y = __fdividef(1.f - t, 1.f + t);
    return copysignf(y, x);
}
// broadcast lane u's value of v to all lanes (VALU pipe, no LDS)
__device__ __forceinline__ float bcast(float v, int u) {
    return __uint_as_float(__builtin_amdgcn_readlane(__float_as_uint(v), u));
}

__global__ __launch_bounds__(512) void k_all(
    const float* __restrict__ x, const int* __restrict__ lens,
    float* __restrict__ hA, float* __restrict__ hB,
    const float* __restrict__ A, const float* __restrict__ Wmsg,
    const float* __restrict__ bmsg, const float* __restrict__ Wg,
    const float* __restrict__ Ug, const float* __restrict__ bg,
    const float* __restrict__ fcw, const float* __restrict__ fcb,
    float* __restrict__ partial, unsigned int* __restrict__ flags,
    float* __restrict__ out) {
    __shared__ float red[8 * NCLS];
    int tid = threadIdx.x;
    int wave = tid >> 6, lane = tid & 63;
    int b = blockIdx.x >> 2;
    int q = blockIdx.x & 3;
    // wave-uniform row base; readfirstlane keeps A addresses scalar-provable
    int n0 = __builtin_amdgcn_readfirstlane(q * 32 + wave * RPW);

    int idx = lens[b] - 1;
    idx = idx < 0 ? 0 : (idx > S - 1 ? S - 1 : idx);
    const float* xsrc = x + (size_t)(b * S + idx) * N * U;
    float* h0 = hA + (size_t)b * N * U;
    float* h1 = hB + (size_t)b * N * U;
    unsigned int* flg = flags + b * 32;  // 128-B spaced per-batch flag

    for (int step = 0; step < 6; ++step) {
        int l = step >= 3 ? 1 : 0;
        // step0 reads x; step t>0 reads output of t-1; out(t) = (t&1)? h1:h0
        const float* hsrc = (step == 0) ? xsrc : ((step & 1) ? h0 : h1);
        float* hdst = (step & 1) ? h1 : h0;

        float hv[RPW];
#pragma unroll
        for (int r = 0; r < RPW; ++r) hv[r] = hsrc[(n0 + r) * U + lane];

        // ---- aggregate: s[r][e] = sum_m A[b,e,n0+r,m] * h[m][lane]
        float s[RPW][E];
#pragma unroll
        for (int r = 0; r < RPW; ++r) { s[r][0] = 0.f; s[r][1] = 0.f; }
        {
            const float4* Ap[E][RPW];
#pragma unroll
            for (int e = 0; e < E; ++e)
#pragma unroll
                for (int r = 0; r < RPW; ++r)
                    Ap[e][r] = (const float4*)(A + (((size_t)b * E + e) * N + n0 + r) * N);
#pragma unroll 2
            for (int m4 = 0; m4 < N / 4; ++m4) {
                float q0 = hsrc[(m4 * 4 + 0) * U + lane];
                float q1 = hsrc[(m4 * 4 + 1) * U + lane];
                float q2 = hsrc[(m4 * 4 + 2) * U + lane];
                float q3 = hsrc[(m4 * 4 + 3) * U + lane];
#pragma unroll
                for (int e = 0; e < E; ++e)
#pragma unroll
                    for (int r = 0; r < RPW; ++r) {
                        float4 a = Ap[e][r][m4];
                        s[r][e] = fmaf(a.x, q0, s[r][e]);
                        s[r][e] = fmaf(a.y, q1, s[r][e]);
                        s[r][e] = fmaf(a.z, q2, s[r][e]);
                        s[r][e] = fmaf(a.w, q3, s[r][e]);
                    }
            }
        }

        // ---- a[r] = sum_e s[r][e] @ Wmsg[l][e] + bmsg[l] (readlane bcast)
        float bm = bmsg[l * U + lane];
        float av[RPW];
#pragma unroll
        for (int r = 0; r < RPW; ++r) av[r] = bm;
        {
            const float* W0 = Wmsg + (size_t)(l * E + 0) * U * U + lane;
            const float* W1 = W0 + U * U;
#pragma unroll 16
            for (int u = 0; u < U; ++u) {
                float w = W0[u * U];
#pragma unroll
                for (int r = 0; r < RPW; ++r) av[r] = fmaf(bcast(s[r][0], u), w, av[r]);
            }
#pragma unroll 16
            for (int u = 0; u < U; ++u) {
                float w = W1[u * U];
#pragma unroll
                for (int r = 0; r < RPW; ++r) av[r] = fmaf(bcast(s[r][1], u), w, av[r]);
            }
        }

        // ---- gate matmuls (lane = output column v)
        const float* Wg0 = Wg + (size_t)l * 3 * U * U + lane;
        const float* Wg1 = Wg0 + U * U;
        const float* Wg2 = Wg1 + U * U;
        const float* Ug0 = Ug + (size_t)l * 3 * U * U + lane;
        const float* Ug1 = Ug0 + U * U;
        const float* Ug2 = Ug1 + U * U;
        float bz = bg[(l * 3 + 0) * U + lane];
        float br = bg[(l * 3 + 1) * U + lane];
        float bcc = bg[(l * 3 + 2) * U + lane];
        float accz[RPW], accr[RPW], accc[RPW];
#pragma unroll
        for (int r = 0; r < RPW; ++r) { accz[r] = bz; accr[r] = br; accc[r] = bcc; }
#pragma unroll 8
        for (int u = 0; u < U; ++u) {
            float w0 = Wg0[u * U], w1 = Wg1[u * U], w2 = Wg2[u * U];
            float g0 = Ug0[u * U], g1 = Ug1[u * U];
#pragma unroll
            for (int r = 0; r < RPW; ++r) {
                float a = bcast(av[r], u);
                float h = bcast(hv[r], u);
                accz[r] = fmaf(a, w0, accz[r]); accz[r] = fmaf(h, g0, accz[r]);
                accr[r] = fmaf(a, w1, accr[r]); accr[r] = fmaf(h, g1, accr[r]);
                accc[r] = fmaf(a, w2, accc[r]);
            }
        }
        float rh[RPW];
#pragma unroll
        for (int r = 0; r < RPW; ++r) rh[r] = sigmoid_f(accr[r]) * hv[r];
#pragma unroll 16
        for (int u = 0; u < U; ++u) {
            float g2 = Ug2[u * U];
#pragma unroll
            for (int r = 0; r < RPW; ++r) accc[r] = fmaf(bcast(rh[r], u), g2, accc[r]);
        }
        float hn[RPW];
#pragma unroll
        for (int r = 0; r < RPW; ++r) {
            float zg = sigmoid_f(accz[r]);
            hn[r] = (1.f - zg) * hv[r] + zg * tanh_f(accc[r]);
        }

        if (step < 5) {
#pragma unroll
            for (int r = 0; r < RPW; ++r) hdst[(n0 + r) * U + lane] = hn[r];
        } else {
            // classification partial over this block's 32 rows
            float lg[RPW][NCLS];
#pragma unroll
            for (int r = 0; r < RPW; ++r) {
                float rv = hn[r] > 0.f ? hn[r] : 0.f;
#pragma unroll
                for (int c = 0; c < NCLS; ++c) lg[r][c] = rv * fcw[lane * NCLS + c];
            }
#pragma unroll
            for (int off = 32; off; off >>= 1)
#pragma unroll
                for (int r = 0; r < RPW; ++r)
#pragma unroll
                    for (int c = 0; c < NCLS; ++c) lg[r][c] += __shfl_xor(lg[r][c], off, 64);
            if (lane == 0) {
#pragma unroll
                for (int c = 0; c < NCLS; ++c)
                    red[wave * NCLS + c] =
                        fmaxf(fmaxf(lg[0][c], lg[1][c]), fmaxf(lg[2][c], lg[3][c]));
            }
            __syncthreads();
            if (tid < NCLS) {
                float m = red[tid];
                for (int w = 1; w < 8; ++w) m = fmaxf(m, red[w * NCLS + tid]);
                partial[(size_t)(b * NBLK + q) * NCLS + tid] = m;
            }
        }

        // ---- 4-block batch barrier: release fence + monotone flag + acquire
        __syncthreads();  // all waves' stores drained (vmcnt0 before s_barrier)
        if (tid == 0) {
            __threadfence();        // agent-scope release (L2 writeback)
            atomicAdd(flg, 1u);     // device-scope by default
            unsigned int tgt = (unsigned)NBLK * (step + 1);
            int it = 0;
            while (__hip_atomic_load(flg, __ATOMIC_ACQUIRE,
                                     __HIP_MEMORY_SCOPE_AGENT) < tgt) {
                __builtin_amdgcn_s_sleep(2);
                if (++it > (1 << 18)) break;  // bailout: wrong answer, not hang
            }
        }
        __syncthreads();
    }

    // ---- final: out[b][c] = max over 4 block-partials + fc_b
    if (q == 0 && tid < NCLS) {
        float m = -3.4e38f;
        for (int jj = 0; jj < NBLK; ++jj)
            m = fmaxf(m, partial[(size_t)(b * NBLK + jj) * NCLS + tid]);
        out[b * NCLS + tid] = m + fcb[tid];
    }
}

// ---------------------------------------------------------------------------
extern "C" void kernel_launch(void* const* d_in, const int* in_sizes, int n_in,
                              void* d_out, int out_size, void* d_ws, size_t ws_size,
                              hipStream_t stream) {
    const float* x    = (const float*)d_in[0];
    const int*   lens = (const int*)d_in[1];
    const float* A    = (const float*)d_in[2];
    const float* Wmsg = (const float*)d_in[3];
    const float* bmsg = (const float*)d_in[4];
    const float* Wg   = (const float*)d_in[5];
    const float* Ug   = (const float*)d_in[6];
    const float* bg   = (const float*)d_in[7];
    const float* fcw  = (const float*)d_in[8];
    const float* fcb  = (const float*)d_in[9];
    float* out = (float*)d_out;

    float* hA      = (float*)d_ws;                    // [B][N][U]
    float* hB      = hA + (size_t)B * N * U;          // [B][N][U]
    float* partial = hB + (size_t)B * N * U;          // [B][NBLK][NCLS]
    unsigned int* flags = (unsigned int*)(partial + (size_t)B * NBLK * NCLS);

    hipMemsetAsync(flags, 0, (size_t)B * 32 * sizeof(unsigned int), stream);
    k_all<<<B * NBLK, 512, 0, stream>>>(x, lens, hA, hB, A, Wmsg, bmsg, Wg, Ug,
                                        bg, fcw, fcb, partial, flags, out);
}

// Round 7
// 224.984 us; speedup vs baseline: 1.1901x; 1.1901x over previous
//
#include <hip/hip_runtime.h>

// Problem constants (match reference)
#define B 32
#define S 32
#define N 128
#define U 64
#define E 2
#define NCLS 5
#define RPW 4    // rows per wave (4 waves x 4 rows = 16 rows per block)

// R14: RPW=4 on the FULL machine via the low-overhead 7-dispatch path.
// Evidence: R13 (RPW=4, 128 blocks) ran all 6 steps in 186us IN-KERNEL on
// half the machine -- 32 rows/CU/step at the same ~31us/step R9 needed for
// 16 rows/CU/step => per-row cost halves with RPW (weight stream amortized
// over 4 rows/wave); the binding constraint is per-CU weight-serving cycles
// (R12's LDS move was neutral: same cycles, different pipe). But R13's
// single-kernel wrapper carried ~81us harness overhead (267 total vs 186
// kernel; R11 same ~87us), while the 7-dispatch path's gap was ~25us.
// So: 7 dispatches, 256 blocks x 256 thr (4 waves x RPW=4 = 16 rows/block,
// 8 blocks/batch) = 1 block/CU, 256 CUs, half of R9's weight traffic.
// Per-row FMA order identical to R13 (absmax 0.0) -> bit-identical output.

__device__ __forceinline__ float sigmoid_f(float x) {
    return __fdividef(1.f, 1.f + __expf(-x));
}
__device__ __forceinline__ float tanh_f(float x) {
    float t = __expf(-2.f * fabsf(x));
    float y = __fdividef(1.f - t, 1.f + t);
    return copysignf(y, x);
}
// broadcast lane u's value of v to all lanes (VALU pipe, no LDS)
__device__ __forceinline__ float bcast(float v, int u) {
    return __uint_as_float(__builtin_amdgcn_readlane(__float_as_uint(v), u));
}

template <int FIRST, int LAST>
__global__ __launch_bounds__(256) void k_step(
    const float* __restrict__ x, const int* __restrict__ lens,
    const float* __restrict__ hin, float* __restrict__ hout,
    const float* __restrict__ A, const float* __restrict__ Wmsg,
    const float* __restrict__ bmsg, const float* __restrict__ Wg,
    const float* __restrict__ Ug, const float* __restrict__ bg,
    const float* __restrict__ fcw, float* __restrict__ partial, int l) {
    __shared__ float red[4 * NCLS];  // LAST tail reduce only
    int tid = threadIdx.x;
    int wave = tid >> 6, lane = tid & 63;
    int b = blockIdx.x >> 3;
    int q = blockIdx.x & 7;
    // wave-uniform row base; readfirstlane keeps A addresses scalar-provable
    int n0 = __builtin_amdgcn_readfirstlane(q * 16 + wave * RPW);

    // h source: global, no staging (h[b]=32KB, L1/L2-resident, shared by the
    // batch's 8 blocks)
    const float* __restrict__ hsrc;
    if (FIRST) {
        int idx = lens[b] - 1;
        idx = idx < 0 ? 0 : (idx > S - 1 ? S - 1 : idx);
        hsrc = x + (size_t)(b * S + idx) * N * U;
    } else {
        hsrc = hin + (size_t)b * N * U;
    }

    float hv[RPW];
#pragma unroll
    for (int r = 0; r < RPW; ++r) hv[r] = hsrc[(n0 + r) * U + lane];

    // ---- aggregate: s[r][e] = sum_m A[b,e,n0+r,m] * h[m][lane]
    float s[RPW][E];
#pragma unroll
    for (int r = 0; r < RPW; ++r) { s[r][0] = 0.f; s[r][1] = 0.f; }
    {
        const float4* Ap[E][RPW];
#pragma unroll
        for (int e = 0; e < E; ++e)
#pragma unroll
            for (int r = 0; r < RPW; ++r)
                Ap[e][r] = (const float4*)(A + (((size_t)b * E + e) * N + n0 + r) * N);
#pragma unroll 2
        for (int m4 = 0; m4 < N / 4; ++m4) {
            float q0 = hsrc[(m4 * 4 + 0) * U + lane];
            float q1 = hsrc[(m4 * 4 + 1) * U + lane];
            float q2 = hsrc[(m4 * 4 + 2) * U + lane];
            float q3 = hsrc[(m4 * 4 + 3) * U + lane];
#pragma unroll
            for (int e = 0; e < E; ++e)
#pragma unroll
                for (int r = 0; r < RPW; ++r) {
                    float4 a = Ap[e][r][m4];
                    s[r][e] = fmaf(a.x, q0, s[r][e]);
                    s[r][e] = fmaf(a.y, q1, s[r][e]);
                    s[r][e] = fmaf(a.z, q2, s[r][e]);
                    s[r][e] = fmaf(a.w, q3, s[r][e]);
                }
        }
    }

    // ---- a[r] = sum_e s[r][e] @ Wmsg[l][e] + bmsg[l] (readlane bcast)
    float bm = bmsg[l * U + lane];
    float av[RPW];
#pragma unroll
    for (int r = 0; r < RPW; ++r) av[r] = bm;
    {
        const float* W0 = Wmsg + (size_t)(l * E + 0) * U * U + lane;
        const float* W1 = W0 + U * U;
#pragma unroll 16
        for (int u = 0; u < U; ++u) {
            float w = W0[u * U];
#pragma unroll
            for (int r = 0; r < RPW; ++r) av[r] = fmaf(bcast(s[r][0], u), w, av[r]);
        }
#pragma unroll 16
        for (int u = 0; u < U; ++u) {
            float w = W1[u * U];
#pragma unroll
            for (int r = 0; r < RPW; ++r) av[r] = fmaf(bcast(s[r][1], u), w, av[r]);
        }
    }

    // ---- gate matmuls (lane = output column v)
    const float* Wg0 = Wg + (size_t)l * 3 * U * U + lane;
    const float* Wg1 = Wg0 + U * U;
    const float* Wg2 = Wg1 + U * U;
    const float* Ug0 = Ug + (size_t)l * 3 * U * U + lane;
    const float* Ug1 = Ug0 + U * U;
    const float* Ug2 = Ug1 + U * U;
    float bz = bg[(l * 3 + 0) * U + lane];
    float br = bg[(l * 3 + 1) * U + lane];
    float bcc = bg[(l * 3 + 2) * U + lane];
    float accz[RPW], accr[RPW], accc[RPW];
#pragma unroll
    for (int r = 0; r < RPW; ++r) { accz[r] = bz; accr[r] = br; accc[r] = bcc; }
#pragma unroll 8
    for (int u = 0; u < U; ++u) {
        float w0 = Wg0[u * U], w1 = Wg1[u * U], w2 = Wg2[u * U];
        float g0 = Ug0[u * U], g1 = Ug1[u * U];
#pragma unroll
        for (int r = 0; r < RPW; ++r) {
            float a = bcast(av[r], u);
            float h = bcast(hv[r], u);
            accz[r] = fmaf(a, w0, accz[r]); accz[r] = fmaf(h, g0, accz[r]);
            accr[r] = fmaf(a, w1, accr[r]); accr[r] = fmaf(h, g1, accr[r]);
            accc[r] = fmaf(a, w2, accc[r]);
        }
    }
    float rh[RPW];
#pragma unroll
    for (int r = 0; r < RPW; ++r) rh[r] = sigmoid_f(accr[r]) * hv[r];
#pragma unroll 16
    for (int u = 0; u < U; ++u) {
        float g2 = Ug2[u * U];
#pragma unroll
        for (int r = 0; r < RPW; ++r) accc[r] = fmaf(bcast(rh[r], u), g2, accc[r]);
    }
    float hn[RPW];
#pragma unroll
    for (int r = 0; r < RPW; ++r) {
        float zg = sigmoid_f(accz[r]);
        hn[r] = (1.f - zg) * hv[r] + zg * tanh_f(accc[r]);
    }

    if (!LAST) {
#pragma unroll
        for (int r = 0; r < RPW; ++r)
            hout[((size_t)b * N + n0 + r) * U + lane] = hn[r];
    } else {
        // classification partial over this block's 16 rows
        float lg[RPW][NCLS];
#pragma unroll
        for (int r = 0; r < RPW; ++r) {
            float rv = hn[r] > 0.f ? hn[r] : 0.f;
#pragma unroll
            for (int c = 0; c < NCLS; ++c) lg[r][c] = rv * fcw[lane * NCLS + c];
        }
#pragma unroll
        for (int off = 32; off; off >>= 1)
#pragma unroll
            for (int r = 0; r < RPW; ++r)
#pragma unroll
                for (int c = 0; c < NCLS; ++c) lg[r][c] += __shfl_xor(lg[r][c], off, 64);
        if (lane == 0) {
#pragma unroll
            for (int c = 0; c < NCLS; ++c)
                red[wave * NCLS + c] =
                    fmaxf(fmaxf(lg[0][c], lg[1][c]), fmaxf(lg[2][c], lg[3][c]));
        }
        __syncthreads();
        if (tid < NCLS) {
            float m = red[tid];
            for (int w = 1; w < 4; ++w) m = fmaxf(m, red[w * NCLS + tid]);
            partial[(size_t)(b * 8 + q) * NCLS + tid] = m;
        }
    }
}

// ---------------------------------------------------------------------------
// k_final: out[b][c] = max over 8 block-partials + fc_b
__global__ void k_final(const float* __restrict__ partial, const float* __restrict__ fcb,
                        float* __restrict__ out) {
    int b = blockIdx.x, c = threadIdx.x;
    if (c < NCLS) {
        float m = -3.4e38f;
        for (int jj = 0; jj < 8; ++jj)
            m = fmaxf(m, partial[(size_t)(b * 8 + jj) * NCLS + c]);
        out[b * NCLS + c] = m + fcb[c];
    }
}

// ---------------------------------------------------------------------------
extern "C" void kernel_launch(void* const* d_in, const int* in_sizes, int n_in,
                              void* d_out, int out_size, void* d_ws, size_t ws_size,
                              hipStream_t stream) {
    const float* x    = (const float*)d_in[0];
    const int*   lens = (const int*)d_in[1];
    const float* A    = (const float*)d_in[2];
    const float* Wmsg = (const float*)d_in[3];
    const float* bmsg = (const float*)d_in[4];
    const float* Wg   = (const float*)d_in[5];
    const float* Ug   = (const float*)d_in[6];
    const float* bg   = (const float*)d_in[7];
    const float* fcw  = (const float*)d_in[8];
    const float* fcb  = (const float*)d_in[9];
    float* out = (float*)d_out;

    float* hA      = (float*)d_ws;                   // [B][N][U]
    float* hB      = hA + (size_t)B * N * U;         // [B][N][U]
    float* partial = hB + (size_t)B * N * U;         // [B][8][NCLS]

    // steps 0-2: layer 0; steps 3-5: layer 1
    k_step<1, 0><<<B * 8, 256, 0, stream>>>(x, lens, nullptr, hA, A, Wmsg, bmsg, Wg, Ug, bg, fcw, partial, 0);
    k_step<0, 0><<<B * 8, 256, 0, stream>>>(x, lens, hA, hB, A, Wmsg, bmsg, Wg, Ug, bg, fcw, partial, 0);
    k_step<0, 0><<<B * 8, 256, 0, stream>>>(x, lens, hB, hA, A, Wmsg, bmsg, Wg, Ug, bg, fcw, partial, 0);
    k_step<0, 0><<<B * 8, 256, 0, stream>>>(x, lens, hA, hB, A, Wmsg, bmsg, Wg, Ug, bg, fcw, partial, 1);
    k_step<0, 0><<<B * 8, 256, 0, stream>>>(x, lens, hB, hA, A, Wmsg, bmsg, Wg, Ug, bg, fcw, partial, 1);
    k_step<0, 1><<<B * 8, 256, 0, stream>>>(x, lens, hA, hB, A, Wmsg, bmsg, Wg, Ug, bg, fcw, partial, 1);
    k_final<<<B, 64, 0, stream>>>(partial, fcb, out);
}

// Round 8
// 195.975 us; speedup vs baseline: 1.3662x; 1.1480x over previous
//
#include <hip/hip_runtime.h>

// Problem constants (match reference)
#define B 32
#define S 32
#define N 128
#define U 64
#define E 2
#define NCLS 5

// R15: split-K=2. Traffic theories are dead: per-CU weight bytes {0.5,1,2}MB
// /step (R14,R9,R10) -> {225,209,226}us. R13 counters: active-SIMD VALUBusy
// ~47% at 2 waves/SIMD -> half issue, half stall. Only untried corner: more
// TLP at CONSTANT per-CU traffic. Two waves share each row pair: wave k of a
// pair handles m-half (aggregate) and u-half (msg/gates/rh); partials meet in
// LDS (gather+add), 4 syncthreads/step. 512 blocks x 512thr = 2 blocks/CU,
// 16 waves/CU, 4/SIMD (2x R9), per-wave stream halved, per-CU bytes == R9.
// NOTE: dot-products are re-associated (p0+p1) -> absmax becomes ~1e-5-level
// (was 0.0); intentionally testing harness tolerance.

__device__ __forceinline__ float sigmoid_f(float x) {
    return __fdividef(1.f, 1.f + __expf(-x));
}
__device__ __forceinline__ float tanh_f(float x) {
    float t = __expf(-2.f * fabsf(x));
    float y = __fdividef(1.f - t, 1.f + t);
    return copysignf(y, x);
}
// broadcast lane u's value of v to all lanes (VALU pipe, no LDS)
__device__ __forceinline__ float bcast(float v, int u) {
    return __uint_as_float(__builtin_amdgcn_readlane(__float_as_uint(v), u));
}

template <int FIRST, int LAST>
__global__ __launch_bounds__(512, 2) void k_step(
    const float* __restrict__ x, const int* __restrict__ lens,
    const float* __restrict__ hin, float* __restrict__ hout,
    const float* __restrict__ A, const float* __restrict__ Wmsg,
    const float* __restrict__ bmsg, const float* __restrict__ Wg,
    const float* __restrict__ Ug, const float* __restrict__ bg,
    const float* __restrict__ fcw, float* __restrict__ partial, int l) {
    // partial-reduce buffers: [group][khalf][...][lane]
    __shared__ float sred[4][2][2][2][64];   // [g][k][row][edge][lane]  8 KB
    __shared__ float avred[4][2][2][64];     // [g][k][row][lane]        4 KB
    __shared__ float gred[4][2][3][2][64];   // [g][k][zrc][row][lane]  12 KB
    __shared__ float c2red[4][2][2][64];     // [g][k][row][lane]        4 KB
    __shared__ float red[4 * NCLS];
    int tid = threadIdx.x;
    int wave = tid >> 6, lane = tid & 63;
    int g = wave & 3;        // row group (2 rows each)
    int k = wave >> 2;       // split half: 0 or 1
    int b = blockIdx.x >> 4;
    int j = blockIdx.x & 15;
    int n0 = __builtin_amdgcn_readfirstlane(j * 8 + g * 2);
    int u0 = __builtin_amdgcn_readfirstlane(k * 32);   // this wave's u-range
    int m0 = __builtin_amdgcn_readfirstlane(k * 64);   // this wave's m-range

    const float* __restrict__ hsrc;
    if (FIRST) {
        int idx = lens[b] - 1;
        idx = idx < 0 ? 0 : (idx > S - 1 ? S - 1 : idx);
        hsrc = x + (size_t)(b * S + idx) * N * U;
    } else {
        hsrc = hin + (size_t)b * N * U;
    }

    float hv0 = hsrc[(n0 + 0) * U + lane];
    float hv1 = hsrc[(n0 + 1) * U + lane];

    // ---- aggregate partials over this wave's m-half
    float s00 = 0.f, s01 = 0.f, s10 = 0.f, s11 = 0.f;  // [row][edge]
    {
        const float4* A00 = (const float4*)(A + (((size_t)b * E + 0) * N + n0 + 0) * N + m0);
        const float4* A10 = (const float4*)(A + (((size_t)b * E + 0) * N + n0 + 1) * N + m0);
        const float4* A01 = (const float4*)(A + (((size_t)b * E + 1) * N + n0 + 0) * N + m0);
        const float4* A11 = (const float4*)(A + (((size_t)b * E + 1) * N + n0 + 1) * N + m0);
#pragma unroll 8
        for (int m4 = 0; m4 < 16; ++m4) {
            float4 a00 = A00[m4], a10 = A10[m4], a01 = A01[m4], a11 = A11[m4];
            float q0 = hsrc[(m0 + m4 * 4 + 0) * U + lane];
            float q1 = hsrc[(m0 + m4 * 4 + 1) * U + lane];
            float q2 = hsrc[(m0 + m4 * 4 + 2) * U + lane];
            float q3 = hsrc[(m0 + m4 * 4 + 3) * U + lane];
            s00 = fmaf(a00.x, q0, s00); s00 = fmaf(a00.y, q1, s00);
            s00 = fmaf(a00.z, q2, s00); s00 = fmaf(a00.w, q3, s00);
            s10 = fmaf(a10.x, q0, s10); s10 = fmaf(a10.y, q1, s10);
            s10 = fmaf(a10.z, q2, s10); s10 = fmaf(a10.w, q3, s10);
            s01 = fmaf(a01.x, q0, s01); s01 = fmaf(a01.y, q1, s01);
            s01 = fmaf(a01.z, q2, s01); s01 = fmaf(a01.w, q3, s01);
            s11 = fmaf(a11.x, q0, s11); s11 = fmaf(a11.y, q1, s11);
            s11 = fmaf(a11.z, q2, s11); s11 = fmaf(a11.w, q3, s11);
        }
    }
    sred[g][k][0][0][lane] = s00;
    sred[g][k][0][1][lane] = s01;
    sred[g][k][1][0][lane] = s10;
    sred[g][k][1][1][lane] = s11;
    __syncthreads();
    s00 = sred[g][0][0][0][lane] + sred[g][1][0][0][lane];
    s01 = sred[g][0][0][1][lane] + sred[g][1][0][1][lane];
    s10 = sred[g][0][1][0][lane] + sred[g][1][1][0][lane];
    s11 = sred[g][0][1][1][lane] + sred[g][1][1][1][lane];

    // ---- msg partials over this wave's u-half (bias carried by k==0)
    float av0, av1;
    {
        float bm = (k == 0) ? bmsg[l * U + lane] : 0.f;
        av0 = bm; av1 = bm;
        const float* W0 = Wmsg + (size_t)(l * E + 0) * U * U + lane;
        const float* W1 = W0 + U * U;
#pragma unroll 16
        for (int uu = 0; uu < 32; ++uu) {
            int u = u0 + uu;
            float w = W0[u * U];
            av0 = fmaf(bcast(s00, u), w, av0);
            av1 = fmaf(bcast(s10, u), w, av1);
        }
#pragma unroll 16
        for (int uu = 0; uu < 32; ++uu) {
            int u = u0 + uu;
            float w = W1[u * U];
            av0 = fmaf(bcast(s01, u), w, av0);
            av1 = fmaf(bcast(s11, u), w, av1);
        }
    }
    avred[g][k][0][lane] = av0;
    avred[g][k][1][lane] = av1;
    __syncthreads();
    av0 = avred[g][0][0][lane] + avred[g][1][0][lane];
    av1 = avred[g][0][1][lane] + avred[g][1][1][lane];

    // ---- gate matmul partials over this wave's u-half
    const float* Wg0 = Wg + (size_t)l * 3 * U * U + lane;
    const float* Wg1 = Wg0 + U * U;
    const float* Wg2 = Wg1 + U * U;
    const float* Ug0 = Ug + (size_t)l * 3 * U * U + lane;
    const float* Ug1 = Ug0 + U * U;
    const float* Ug2 = Ug1 + U * U;
    float accz0, accz1, accr0, accr1, accc0, accc1;
    {
        float bz = (k == 0) ? bg[(l * 3 + 0) * U + lane] : 0.f;
        float br = (k == 0) ? bg[(l * 3 + 1) * U + lane] : 0.f;
        float bcc = (k == 0) ? bg[(l * 3 + 2) * U + lane] : 0.f;
        accz0 = bz; accz1 = bz;
        accr0 = br; accr1 = br;
        accc0 = bcc; accc1 = bcc;
#pragma unroll 8
        for (int uu = 0; uu < 32; ++uu) {
            int u = u0 + uu;
            float w0 = Wg0[u * U], w1 = Wg1[u * U], w2 = Wg2[u * U];
            float g0 = Ug0[u * U], g1 = Ug1[u * U];
            float a0 = bcast(av0, u), a1 = bcast(av1, u);
            float h0 = bcast(hv0, u), h1 = bcast(hv1, u);
            accz0 = fmaf(a0, w0, accz0); accz0 = fmaf(h0, g0, accz0);
            accz1 = fmaf(a1, w0, accz1); accz1 = fmaf(h1, g0, accz1);
            accr0 = fmaf(a0, w1, accr0); accr0 = fmaf(h0, g1, accr0);
            accr1 = fmaf(a1, w1, accr1); accr1 = fmaf(h1, g1, accr1);
            accc0 = fmaf(a0, w2, accc0);
            accc1 = fmaf(a1, w2, accc1);
        }
    }
    gred[g][k][0][0][lane] = accz0; gred[g][k][0][1][lane] = accz1;
    gred[g][k][1][0][lane] = accr0; gred[g][k][1][1][lane] = accr1;
    gred[g][k][2][0][lane] = accc0; gred[g][k][2][1][lane] = accc1;
    __syncthreads();
    accz0 = gred[g][0][0][0][lane] + gred[g][1][0][0][lane];
    accz1 = gred[g][0][0][1][lane] + gred[g][1][0][1][lane];
    accr0 = gred[g][0][1][0][lane] + gred[g][1][1][0][lane];
    accr1 = gred[g][0][1][1][lane] + gred[g][1][1][1][lane];
    accc0 = gred[g][0][2][0][lane] + gred[g][1][2][0][lane];
    accc1 = gred[g][0][2][1][lane] + gred[g][1][2][1][lane];

    // ---- rh matmul partials over this wave's u-half (rh identical on both)
    float rh0 = sigmoid_f(accr0) * hv0;
    float rh1 = sigmoid_f(accr1) * hv1;
    float c20 = 0.f, c21 = 0.f;
#pragma unroll 16
    for (int uu = 0; uu < 32; ++uu) {
        int u = u0 + uu;
        float g2 = Ug2[u * U];
        c20 = fmaf(bcast(rh0, u), g2, c20);
        c21 = fmaf(bcast(rh1, u), g2, c21);
    }
    c2red[g][k][0][lane] = c20;
    c2red[g][k][1][lane] = c21;
    __syncthreads();
    accc0 += c2red[g][0][0][lane] + c2red[g][1][0][lane];
    accc1 += c2red[g][0][1][lane] + c2red[g][1][1][lane];

    float zg0 = sigmoid_f(accz0), zg1 = sigmoid_f(accz1);
    float hn0 = (1.f - zg0) * hv0 + zg0 * tanh_f(accc0);
    float hn1 = (1.f - zg1) * hv1 + zg1 * tanh_f(accc1);

    if (!LAST) {
        if (k == 0) {
            hout[((size_t)b * N + n0 + 0) * U + lane] = hn0;
            hout[((size_t)b * N + n0 + 1) * U + lane] = hn1;
        }
    } else {
        // classification partial over this block's 8 rows (k==0 waves own it)
        float lg0[NCLS], lg1[NCLS];
        float rv0 = hn0 > 0.f ? hn0 : 0.f;
        float rv1 = hn1 > 0.f ? hn1 : 0.f;
#pragma unroll
        for (int c = 0; c < NCLS; c++) {
            float w = fcw[lane * NCLS + c];
            lg0[c] = rv0 * w;
            lg1[c] = rv1 * w;
        }
#pragma unroll
        for (int off = 32; off; off >>= 1) {
#pragma unroll
            for (int c = 0; c < NCLS; c++) {
                lg0[c] += __shfl_xor(lg0[c], off, 64);
                lg1[c] += __shfl_xor(lg1[c], off, 64);
            }
        }
        if (k == 0 && lane == 0) {
#pragma unroll
            for (int c = 0; c < NCLS; c++) red[g * NCLS + c] = fmaxf(lg0[c], lg1[c]);
        }
        __syncthreads();
        if (tid < NCLS) {
            float m = red[tid];
            for (int w = 1; w < 4; ++w) m = fmaxf(m, red[w * NCLS + tid]);
            partial[(size_t)(b * 16 + j) * NCLS + tid] = m;
        }
    }
}

// ---------------------------------------------------------------------------
// k_final: out[b][c] = max over 16 block-partials + fc_b
__global__ void k_final(const float* __restrict__ partial, const float* __restrict__ fcb,
                        float* __restrict__ out) {
    int b = blockIdx.x, c = threadIdx.x;
    if (c < NCLS) {
        float m = -3.4e38f;
        for (int jj = 0; jj < 16; ++jj)
            m = fmaxf(m, partial[(size_t)(b * 16 + jj) * NCLS + c]);
        out[b * NCLS + c] = m + fcb[c];
    }
}

// ---------------------------------------------------------------------------
extern "C" void kernel_launch(void* const* d_in, const int* in_sizes, int n_in,
                              void* d_out, int out_size, void* d_ws, size_t ws_size,
                              hipStream_t stream) {
    const float* x    = (const float*)d_in[0];
    const int*   lens = (const int*)d_in[1];
    const float* A    = (const float*)d_in[2];
    const float* Wmsg = (const float*)d_in[3];
    const float* bmsg = (const float*)d_in[4];
    const float* Wg   = (const float*)d_in[5];
    const float* Ug   = (const float*)d_in[6];
    const float* bg   = (const float*)d_in[7];
    const float* fcw  = (const float*)d_in[8];
    const float* fcb  = (const float*)d_in[9];
    float* out = (float*)d_out;

    float* hA      = (float*)d_ws;                   // [B][N][U]
    float* hB      = hA + (size_t)B * N * U;         // [B][N][U]
    float* partial = hB + (size_t)B * N * U;         // [B][16][NCLS]

    // steps 0-2: layer 0; steps 3-5: layer 1
    k_step<1, 0><<<B * 16, 512, 0, stream>>>(x, lens, nullptr, hA, A, Wmsg, bmsg, Wg, Ug, bg, fcw, partial, 0);
    k_step<0, 0><<<B * 16, 512, 0, stream>>>(x, lens, hA, hB, A, Wmsg, bmsg, Wg, Ug, bg, fcw, partial, 0);
    k_step<0, 0><<<B * 16, 512, 0, stream>>>(x, lens, hB, hA, A, Wmsg, bmsg, Wg, Ug, bg, fcw, partial, 0);
    k_step<0, 0><<<B * 16, 512, 0, stream>>>(x, lens, hA, hB, A, Wmsg, bmsg, Wg, Ug, bg, fcw, partial, 1);
    k_step<0, 0><<<B * 16, 512, 0, stream>>>(x, lens, hB, hA, A, Wmsg, bmsg, Wg, Ug, bg, fcw, partial, 1);
    k_step<0, 1><<<B * 16, 512, 0, stream>>>(x, lens, hA, hB, A, Wmsg, bmsg, Wg, Ug, bg, fcw, partial, 1);
    k_final<<<B, 64, 0, stream>>>(partial, fcb, out);
}